// Round 1
// baseline (623.507 us; speedup 1.0000x reference)
//
#include <hip/hip_runtime.h>
#include <cmath>

#define BB 256
#define TT 512
#define NN 128
#define LN2F 0.6931471805599453f

typedef __bf16 bf16x8 __attribute__((ext_vector_type(8)));
typedef float floatx4 __attribute__((ext_vector_type(4)));

__device__ __forceinline__ float wave_max64(float v) {
    #pragma unroll
    for (int off = 32; off; off >>= 1) v = fmaxf(v, __shfl_xor(v, off));
    return v;
}
__device__ __forceinline__ float wave_sum64(float v) {
    #pragma unroll
    for (int off = 32; off; off >>= 1) v += __shfl_xor(v, off);
    return v;
}
// argmax over 128 values (lane l holds indices 2l, 2l+1); first-index tie-break.
__device__ __forceinline__ int wave_argmax128(float v0, float v1, int l) {
    float m = fmaxf(v0, v1);
    float wm = wave_max64(m);
    unsigned long long ball = __ballot(m == wm);
    int lane = __ffsll(ball) - 1;
    int idx = (v0 == wm) ? (2 * l) : (2 * l + 1);
    return __shfl(idx, lane);
}

__device__ __forceinline__ __bf16 to_bf16(float f) {   // RNE
    unsigned u = __float_as_uint(f);
    unsigned r = (u + 0x7FFFu + ((u >> 16) & 1u)) >> 16;
    union { unsigned short s; __bf16 b; } cv;
    cv.s = (unsigned short)r;
    return cv.b;
}

// Padded state layout: 16-float chunk q starts at word 20q (banks 20q%32 =
// {0,20,8,28,16,4,24,12} -> the 8 chunks' b128 reads cover all 32 banks
// disjointly; same-address lanes broadcast).
__device__ __forceinline__ int padidx16(int i) { return 20 * (i >> 4) + (i & 15); }

// Fully fused CRF kernel. grid = BB, 1024-thread blocks (16 waves), 1 block/CU
// (static LDS deliberately > 80 KiB so two blocks can never co-reside).
//   V (all 16 waves): col jv=(l&7)+8w, 8 lanes/col, 16 i's/lane -> halved
//     per-lane serial depth vs the old 4-lane/col layout. u8 bp in LDS,
//     3-phase parallel backtrace over 16 chunks of 32 steps.
//   S (waves 0-7):   exact copy of the previous MFMA log-norm chain
//     (col js=(l&15)+16w, E=exp(trans) bf16 B-frags, bf16 state dbl-buf,
//     pivot rescale, kacc), sharing the SAME per-step barrier as V.
//   Epilogue: last-tag argmax, lognorm reduce, parallel backtrace, gold-path
//     score, trans copy, all outputs -> single dispatch for the whole op.
__global__ __launch_bounds__(1024, 4) void fused_kernel(
        const float* __restrict__ em, const int* __restrict__ gtags,
        const int* __restrict__ mask, const float* __restrict__ trans,
        float* __restrict__ out_ll, float* __restrict__ out_trans,
        float* __restrict__ outp) {
    const int b = blockIdx.x;
    const int tid = threadIdx.x;
    const int w = tid >> 6;            // 0..15
    const int l = tid & 63;
    const int jv = (l & 7) + 8 * w;    // Viterbi column (8 lanes each)
    const int q = l >> 3;              // i-chunk of 16
    const int i0 = 16 * q;
    const bool sAct = (w < 8);
    const int js = (l & 15) + 16 * (w & 7);   // S column (waves 0-7)
    const int qs = l >> 4;

    // stA/stB oversized (1440 vs 160 used) purely to push static LDS past
    // 80 KiB -> guarantees exactly 1 block per CU (256 blocks / 256 CUs).
    __shared__ __align__(16) float stA[1440], stB[1440];
    __shared__ __align__(16) __bf16 sbf[2][NN];
    __shared__ unsigned char bp_lds[TT * NN];          // 64 KB backpointers
    __shared__ unsigned char tags_lds[TT];
    __shared__ unsigned char map_lds[16 * NN];
    __shared__ int entry_sh[16];
    __shared__ int msk[TT];
    __shared__ float piv[2];
    __shared__ float sfin[NN];
    __shared__ float wsum[16];
    __shared__ float llnorm_sh;
    __shared__ int misc[2];                            // [0]=lastTag [1]=kacc

    if (tid < TT) msk[tid] = mask[b * TT + tid];

    const float* emb = em + (size_t)b * TT * NN;

    // ---- V init ----
    float C[16];
    {
        const float* tc = trans + (size_t)i0 * NN + jv;
        #pragma unroll
        for (int r = 0; r < 16; ++r) C[r] = tc[(size_t)r * NN];
    }
    float st;
    {
        float a0 = emb[jv];
        st = a0;
        if (l < 8) stA[padidx16(jv)] = a0;
    }
    float e_next = emb[NN + jv];

    // ---- S init ----
    bf16x8 Bf[4];
    float ss = 0.f, es_next = 0.f;
    int kacc = 0;
    if (sAct) {
        #pragma unroll
        for (int kc = 0; kc < 4; ++kc) {
            #pragma unroll
            for (int jj = 0; jj < 8; ++jj) {
                int row = kc * 32 + qs * 8 + jj;
                Bf[kc][jj] = to_bf16(__expf(trans[(size_t)row * NN + js]));
            }
        }
        ss = __expf(emb[js]);
        if (l < 16) sbf[0][js] = to_bf16(ss);
        if (tid == 0) piv[0] = ss;
        es_next = emb[NN + js];
    }
    __syncthreads();

    const float4* apA = (const float4*)(stA + 20 * q);
    const float4* apB = (const float4*)(stB + 20 * q);

    auto STEP = [&](int t, const float4* ap, float* dst) {
        const float e_cur = e_next;
        const float es_cur = es_next;
        if (t + 1 < TT) {
            e_next = emb[(size_t)(t + 1) * NN + jv];
            if (sAct) es_next = emb[(size_t)(t + 1) * NN + js];
        }
        const int m = msk[t];
        // ---- V: max-plus column update with tracked argmax ----
        float m0 = -INFINITY, m1 = -INFINITY, m2 = -INFINITY, m3 = -INFINITY;
        int u0 = 0, u1 = 0, u2 = 0, u3 = 0;
        #pragma unroll
        for (int u = 0; u < 4; ++u) {
            float4 v = ap[u];
            float c0 = v.x + C[4*u+0]; u0 = (c0 > m0) ? u : u0; m0 = fmaxf(m0, c0);
            float c1 = v.y + C[4*u+1]; u1 = (c1 > m1) ? u : u1; m1 = fmaxf(m1, c1);
            float c2 = v.z + C[4*u+2]; u2 = (c2 > m2) ? u : u2; m2 = fmaxf(m2, c2);
            float c3 = v.w + C[4*u+3]; u3 = (c3 > m3) ? u : u3; m3 = fmaxf(m3, c3);
        }
        float bv = m0; int bx = i0 + 4 * u0;
        { int id = i0 + 4*u1 + 1; if (m1 > bv || (m1 == bv && id < bx)) { bv = m1; bx = id; } }
        { int id = i0 + 4*u2 + 2; if (m2 > bv || (m2 == bv && id < bx)) { bv = m2; bx = id; } }
        { int id = i0 + 4*u3 + 3; if (m3 > bv || (m3 == bv && id < bx)) { bv = m3; bx = id; } }
        #pragma unroll
        for (int off = 8; off <= 32; off <<= 1) {
            float ov = __shfl_xor(bv, off);
            int oi = __shfl_xor(bx, off);
            if (ov > bv || (ov == bv && oi < bx)) { bv = ov; bx = oi; }
        }
        if (l < 8) {
            float an; int bp;
            if (m) { an = bv + e_cur; bp = bx; }   // plain add = reference-exact
            else   { an = st;         bp = jv; }   // identity bp when masked
            st = an;
            dst[padidx16(jv)] = an;
            bp_lds[t * NN + jv] = (unsigned char)bp;
        }
        // ---- S: scaled-exp forward recursion via MFMA (waves 0-7) ----
        if (sAct) {
            if (m) {
                const int p = (t - 1) & 1;
                const __bf16* sp = sbf[p];
                floatx4 acc = {0.f, 0.f, 0.f, 0.f};
                #pragma unroll
                for (int kc = 0; kc < 4; ++kc) {
                    bf16x8 a = *(const bf16x8*)(sp + kc * 32 + qs * 8);
                    acc = __builtin_amdgcn_mfma_f32_16x16x32_bf16(a, Bf[kc], acc, 0, 0, 0);
                }
                float dot = acc[0];                // rows identical -> regs equal
                const float pv = piv[p];
                const int k = (int)(__float_as_uint(pv) >> 23) - 127;
                const float scale = __uint_as_float((unsigned)(127 - k) << 23);  // 2^-k
                ss = dot * scale * __expf(es_cur);
                if (tid == 0) kacc += k;
            }
            const int qb = t & 1;
            if (l < 16) sbf[qb][js] = to_bf16(ss);
            if (tid == 0) piv[qb] = ss;
        }
        __syncthreads();   // single barrier serves both chains (2-buf ping-pong)
    };

    for (int t = 1; t < TT - 1; t += 2) {
        STEP(t, apA, stB);
        STEP(t + 1, apB, stA);
    }
    STEP(TT - 1, apA, stB);   // final alpha in stB

    // ---- epilogue ----
    if (sAct && l < 16) sfin[js] = ss;
    if (tid == 0) misc[1] = kacc;
    if (w == 0) {   // last-tag argmax (exact, first-index ties)
        float a0 = stB[padidx16(2 * l)], a1 = stB[padidx16(2 * l + 1)];
        int tg = wave_argmax128(a0, a1, l);
        if (l == 0) { misc[0] = tg; tags_lds[TT - 1] = (unsigned char)tg; }
    }
    if (tid < 64) out_trans[b * 64 + tid] = trans[b * 64 + tid];  // folded copy
    __syncthreads();
    if (w == 1) {   // lognorm for this batch
        float v = sfin[2 * l] + sfin[2 * l + 1];
        v = wave_sum64(v);
        if (l == 0) llnorm_sh = __logf(v) + (float)misc[1] * LN2F;
    }
    // Phase 1: each wave maps all 128 entry tags through its 32-step chunk.
    const int lo = 32 * w + 1;
    const int hi = (w == 15) ? (TT - 1) : (32 * w + 32);
    {
        int tA = 2 * l, tB = 2 * l + 1;
        for (int t = hi; t >= lo; --t) {
            tA = bp_lds[t * NN + tA];
            tB = bp_lds[t * NN + tB];
        }
        map_lds[w * NN + 2 * l]     = (unsigned char)tA;
        map_lds[w * NN + 2 * l + 1] = (unsigned char)tB;
    }
    __syncthreads();
    // Phase 2: compose chunk maps -> true entry tag per chunk.
    if (tid == 0) {
        int e = misc[0];
        entry_sh[15] = e;
        for (int c = 15; c >= 1; --c) { e = map_lds[c * NN + e]; entry_sh[c - 1] = e; }
    }
    __syncthreads();
    // Phase 3: re-trace each chunk from its true entry.
    if (l == 0) {
        int tg = entry_sh[w];
        for (int t = hi; t >= lo; --t) {
            tg = bp_lds[t * NN + tg];
            tags_lds[t - 1] = (unsigned char)tg;
        }
    }
    __syncthreads();
    // Gold-path score (input tag_ids) + prediction output + final LL.
    float acc = 0.f;
    if (tid < TT) {
        outp[(size_t)b * TT + tid] = (float)tags_lds[tid];
        int tg = gtags[b * TT + tid];
        float mf = (float)msk[tid];
        acc = emb[(size_t)tid * NN + tg] * mf;
        if (tid >= 1) {
            int tp = gtags[b * TT + tid - 1];
            acc += trans[tp * NN + tg] * mf;
        }
    }
    acc = wave_sum64(acc);
    if (l == 0) wsum[w] = acc;
    __syncthreads();
    if (tid == 0) {
        float s = 0.f;
        #pragma unroll
        for (int i = 0; i < 16; ++i) s += wsum[i];
        out_ll[b] = s - llnorm_sh;
    }
}

extern "C" void kernel_launch(void* const* d_in, const int* in_sizes, int n_in,
                              void* d_out, int out_size, void* d_ws, size_t ws_size,
                              hipStream_t stream) {
    const float* em = (const float*)d_in[0];
    const int* gtags = (const int*)d_in[1];
    const int* mask = (const int*)d_in[2];
    const float* trans = (const float*)d_in[3];

    float* out = (float*)d_out;
    float* out_ll = out;
    float* out_trans = out + BB;
    float* out_pred = out + BB + NN * NN;

    hipLaunchKernelGGL(fused_kernel, dim3(BB), dim3(1024), 0, stream,
                       em, gtags, mask, trans, out_ll, out_trans, out_pred);
}

// Round 3
// 524.769 us; speedup vs baseline: 1.1882x; 1.1882x over previous
//
#include <hip/hip_runtime.h>
#include <cmath>

#define BB 256
#define TT 512
#define NN 128
#define LN2F 0.6931471805599453f

typedef __bf16 bf16x8 __attribute__((ext_vector_type(8)));
typedef float floatx4 __attribute__((ext_vector_type(4)));

__device__ __forceinline__ float wave_max64(float v) {
    #pragma unroll
    for (int off = 32; off; off >>= 1) v = fmaxf(v, __shfl_xor(v, off));
    return v;
}
__device__ __forceinline__ float wave_sum64(float v) {
    #pragma unroll
    for (int off = 32; off; off >>= 1) v += __shfl_xor(v, off);
    return v;
}
// argmax over 128 values (lane l holds indices 2l, 2l+1); first-index tie-break.
__device__ __forceinline__ int wave_argmax128(float v0, float v1, int l) {
    float m = fmaxf(v0, v1);
    float wm = wave_max64(m);
    unsigned long long ball = __ballot(m == wm);
    int lane = __ffsll(ball) - 1;
    int idx = (v0 == wm) ? (2 * l) : (2 * l + 1);
    return __shfl(idx, lane);
}

__device__ __forceinline__ __bf16 to_bf16(float f) {   // RNE
    unsigned u = __float_as_uint(f);
    unsigned r = (u + 0x7FFFu + ((u >> 16) & 1u)) >> 16;
    union { unsigned short s; __bf16 b; } cv;
    cv.s = (unsigned short)r;
    return cv.b;
}

// Padded state layout: 32-float chunk c starts at word 36c (bank offset 4c).
__device__ __forceinline__ int padidx(int i) { return 36 * (i >> 5) + (i & 31); }

// Forward. grid = 2*BB, 512-thread blocks (8 waves), 2 blocks/CU.
//   Blocks 0..BB-1   : Viterbi for batch b=bi (tracked argmax, u8 bp in LDS,
//                      3-phase parallel backtrace) + folded trans-copy slice.
//   Blocks BB..2BB-1 : log-norm for batch b=bi-BB via MFMA + folded gold-path
//                      score and final LL (no workspace round-trip).
// Pairing b <-> b+BB puts one V + one S block per CU under linear or
// XCD-round-robin dispatch -> light S chain fills heavy V chain's stalls,
// and the two blocks keep INDEPENDENT barrier domains (fusing them into one
// 16-wave block regressed: R1 measured 587us vs 490us split).
__global__ __launch_bounds__(512, 4) void fwd_kernel(
        const float* __restrict__ em, const int* __restrict__ gtags,
        const int* __restrict__ mask, const float* __restrict__ trans,
        float* __restrict__ out_ll, float* __restrict__ out_trans,
        float* __restrict__ outp) {
    const int bi = blockIdx.x;
    const bool isV = bi < BB;
    const int b = isV ? bi : bi - BB;
    const int tid = threadIdx.x;
    const int w = tid >> 6;
    const int l = tid & 63;
    const int j = (l & 15) + 16 * w;   // column (V: unique per (w,l&15); S: same)
    const int q = l >> 4;              // V: i-chunk of 32; S: quad
    const int i0 = 32 * q;

    __shared__ __align__(16) float stA[144], stB[144];  // V alpha ping-pong
    __shared__ __align__(16) __bf16 sbf[2][NN];         // S state (bf16) dbl-buf
    __shared__ unsigned char bp_lds[TT * NN];           // V: 64 KB backpointers
    __shared__ unsigned char tags_lds[TT];
    __shared__ unsigned char map_lds[8 * NN];
    __shared__ int entry_sh[8];
    __shared__ int msk[TT];
    __shared__ float piv[2];
    __shared__ float sfin[NN];
    __shared__ float wsum[8];
    __shared__ float llnorm_sh;
    __shared__ int misc[2];                             // [0]=lastTag [1]=kacc

    msk[tid] = mask[b * TT + tid];

    const float* emb = em + (size_t)b * TT * NN;

    if (isV) {
        float C[32];
        {
            const float* tc = trans + (size_t)i0 * NN + j;
            #pragma unroll
            for (int r = 0; r < 32; ++r) C[r] = tc[(size_t)r * NN];
        }
        float st = 0.f;
        {
            float a0 = emb[j];
            st = a0;
            if (l < 16) stA[padidx(j)] = a0;
        }
        float e_next = emb[NN + j];
        __syncthreads();

        const float4* apA = (const float4*)(stA + 36 * q);
        const float4* apB = (const float4*)(stB + 36 * q);

        auto VSTEP = [&](int t, const float4* ap, float* dst) {
            const float e_cur = e_next;
            if (t + 1 < TT) e_next = emb[(size_t)(t + 1) * NN + j];
            const int m = msk[t];
            // Issue ALL 8 ds_read_b128 before any consumption: one lgkmcnt
            // wait instead of staggered load/wait/consume (VGPR 52 -> ~90;
            // budget at launch_bounds(512,4) is 128).
            float4 vv[8];
            #pragma unroll
            for (int u = 0; u < 8; ++u) vv[u] = ap[u];
            float m0 = -INFINITY, m1 = -INFINITY, m2 = -INFINITY, m3 = -INFINITY;
            int u0 = 0, u1 = 0, u2 = 0, u3 = 0;
            #pragma unroll
            for (int u = 0; u < 8; ++u) {
                float c0 = vv[u].x + C[4*u+0]; u0 = (c0 > m0) ? u : u0; m0 = fmaxf(m0, c0);
                float c1 = vv[u].y + C[4*u+1]; u1 = (c1 > m1) ? u : u1; m1 = fmaxf(m1, c1);
                float c2 = vv[u].z + C[4*u+2]; u2 = (c2 > m2) ? u : u2; m2 = fmaxf(m2, c2);
                float c3 = vv[u].w + C[4*u+3]; u3 = (c3 > m3) ? u : u3; m3 = fmaxf(m3, c3);
            }
            float bv = m0; int bx = i0 + 4 * u0;
            { int id = i0 + 4*u1 + 1; if (m1 > bv || (m1 == bv && id < bx)) { bv = m1; bx = id; } }
            { int id = i0 + 4*u2 + 2; if (m2 > bv || (m2 == bv && id < bx)) { bv = m2; bx = id; } }
            { int id = i0 + 4*u3 + 3; if (m3 > bv || (m3 == bv && id < bx)) { bv = m3; bx = id; } }
            #pragma unroll
            for (int off = 16; off <= 32; off <<= 1) {
                float ov = __shfl_xor(bv, off);
                int oi = __shfl_xor(bx, off);
                if (ov > bv || (ov == bv && oi < bx)) { bv = ov; bx = oi; }
            }
            if (l < 16) {
                float an; int bp;
                if (m) { an = bv + e_cur; bp = bx; }   // plain add = reference-exact
                else   { an = st;         bp = j;  }   // identity bp when masked
                st = an;
                dst[padidx(j)] = an;
                bp_lds[t * NN + j] = (unsigned char)bp;
            }
            __syncthreads();
        };

        for (int t = 1; t < TT - 1; t += 2) {
            VSTEP(t, apA, stB);
            VSTEP(t + 1, apB, stA);
        }
        VSTEP(TT - 1, apA, stB);   // final alpha in stB

        if (w == 0) {   // last-tag argmax (exact, first-index ties)
            float a0 = stB[padidx(2 * l)], a1 = stB[padidx(2 * l + 1)];
            int tg = wave_argmax128(a0, a1, l);
            if (l == 0) { misc[0] = tg; tags_lds[TT - 1] = (unsigned char)tg; }
        }
        if (tid < 64) out_trans[b * 64 + tid] = trans[b * 64 + tid];  // folded copy
        __syncthreads();
        // Phase 1: each wave maps all 128 entry tags through its 64-step chunk.
        const int lo = 64 * w + 1;
        const int hi = (w == 7) ? (TT - 1) : (64 * w + 64);
        {
            int tA = 2 * l, tB = 2 * l + 1;
            for (int t = hi; t >= lo; --t) {
                tA = bp_lds[t * NN + tA];
                tB = bp_lds[t * NN + tB];
            }
            map_lds[w * NN + 2 * l]     = (unsigned char)tA;
            map_lds[w * NN + 2 * l + 1] = (unsigned char)tB;
        }
        __syncthreads();
        // Phase 2: compose chunk maps -> true entry tag per chunk.
        if (tid == 0) {
            int e = misc[0];
            entry_sh[7] = e;
            for (int c = 7; c >= 1; --c) { e = map_lds[c * NN + e]; entry_sh[c - 1] = e; }
        }
        __syncthreads();
        // Phase 3: re-trace each chunk from its true entry.
        if (l == 0) {
            int tg = entry_sh[w];
            for (int t = hi; t >= lo; --t) {
                tg = bp_lds[t * NN + tg];
                tags_lds[t - 1] = (unsigned char)tg;
            }
        }
        __syncthreads();
        outp[(size_t)b * TT + tid] = (float)tags_lds[tid];
    } else {
        bf16x8 Bf[4];
        #pragma unroll
        for (int kc = 0; kc < 4; ++kc) {
            #pragma unroll
            for (int jj = 0; jj < 8; ++jj) {
                int row = kc * 32 + q * 8 + jj;
                Bf[kc][jj] = to_bf16(__expf(trans[(size_t)row * NN + j]));
            }
        }
        float ss = __expf(emb[j]);
        int kacc = 0;
        if (l < 16) sbf[0][j] = to_bf16(ss);
        if (tid == 0) piv[0] = ss;
        float e_next = emb[NN + j];
        __syncthreads();

        for (int t = 1; t < TT; ++t) {
            const float e_cur = e_next;
            if (t + 1 < TT) e_next = emb[(size_t)(t + 1) * NN + j];
            const int m = msk[t];
            const int p = (t - 1) & 1, qb = t & 1;
            if (m) {
                const __bf16* sp = sbf[p];
                floatx4 acc = {0.f, 0.f, 0.f, 0.f};
                #pragma unroll
                for (int kc = 0; kc < 4; ++kc) {
                    bf16x8 a = *(const bf16x8*)(sp + kc * 32 + q * 8);
                    acc = __builtin_amdgcn_mfma_f32_16x16x32_bf16(a, Bf[kc], acc, 0, 0, 0);
                }
                float dot = acc[0];                    // rows identical -> regs equal
                const float pv = piv[p];
                const int k = (int)(__float_as_uint(pv) >> 23) - 127;
                const float scale = __uint_as_float((unsigned)(127 - k) << 23);  // 2^-k
                ss = dot * scale * __expf(e_cur);
                if (tid == 0) kacc += k;
            }
            if (l < 16) sbf[qb][j] = to_bf16(ss);
            if (tid == 0) piv[qb] = ss;
            __syncthreads();
        }

        if (l < 16) sfin[j] = ss;
        if (tid == 0) misc[1] = kacc;
        __syncthreads();
        if (w == 0) {
            float v = sfin[2 * l] + sfin[2 * l + 1];
            v = wave_sum64(v);
            if (l == 0) llnorm_sh = __logf(v) + (float)misc[1] * LN2F;
        }
        // Folded gold-path score: one t per thread (TT == blockDim).
        float acc = 0.f;
        {
            int tg = gtags[b * TT + tid];
            float mf = (float)msk[tid];
            acc = emb[(size_t)tid * NN + tg] * mf;
            if (tid >= 1) {
                int tp = gtags[b * TT + tid - 1];
                acc += trans[tp * NN + tg] * mf;
            }
        }
        acc = wave_sum64(acc);
        if (l == 0) wsum[w] = acc;
        __syncthreads();
        if (tid == 0) {
            float s = 0.f;
            #pragma unroll
            for (int i = 0; i < 8; ++i) s += wsum[i];
            out_ll[b] = s - llnorm_sh;
        }
    }
}

extern "C" void kernel_launch(void* const* d_in, const int* in_sizes, int n_in,
                              void* d_out, int out_size, void* d_ws, size_t ws_size,
                              hipStream_t stream) {
    const float* em = (const float*)d_in[0];
    const int* gtags = (const int*)d_in[1];
    const int* mask = (const int*)d_in[2];
    const float* trans = (const float*)d_in[3];

    float* out = (float*)d_out;
    float* out_ll = out;
    float* out_trans = out + BB;
    float* out_pred = out + BB + NN * NN;

    hipLaunchKernelGGL(fwd_kernel, dim3(2 * BB), dim3(512), 0, stream,
                       em, gtags, mask, trans, out_ll, out_trans, out_pred);
}

// Round 4
// 521.129 us; speedup vs baseline: 1.1965x; 1.0070x over previous
//
#include <hip/hip_runtime.h>
#include <cmath>

#define BB 256
#define TT 512
#define NN 128
#define LN2F 0.6931471805599453f

typedef __bf16 bf16x8 __attribute__((ext_vector_type(8)));
typedef float floatx4 __attribute__((ext_vector_type(4)));

__device__ __forceinline__ float wave_max64(float v) {
    #pragma unroll
    for (int off = 32; off; off >>= 1) v = fmaxf(v, __shfl_xor(v, off));
    return v;
}
__device__ __forceinline__ float wave_sum64(float v) {
    #pragma unroll
    for (int off = 32; off; off >>= 1) v += __shfl_xor(v, off);
    return v;
}
// argmax over 128 values (lane l holds indices 2l, 2l+1); first-index tie-break.
__device__ __forceinline__ int wave_argmax128(float v0, float v1, int l) {
    float m = fmaxf(v0, v1);
    float wm = wave_max64(m);
    unsigned long long ball = __ballot(m == wm);
    int lane = __ffsll(ball) - 1;
    int idx = (v0 == wm) ? (2 * l) : (2 * l + 1);
    return __shfl(idx, lane);
}

__device__ __forceinline__ __bf16 to_bf16(float f) {   // RNE
    unsigned u = __float_as_uint(f);
    unsigned r = (u + 0x7FFFu + ((u >> 16) & 1u)) >> 16;
    union { unsigned short s; __bf16 b; } cv;
    cv.s = (unsigned short)r;
    return cv.b;
}

// Padded state layout: 32-float chunk c starts at word 36c (bank offset 4c).
__device__ __forceinline__ int padidx(int i) { return 36 * (i >> 5) + (i & 31); }

// Forward. grid = 2*BB, 512-thread blocks (8 waves), 2 blocks/CU.
//   Blocks 0..BB-1   : Viterbi for batch b=bi (tracked argmax, u8 bp in LDS,
//                      3-phase parallel backtrace) + folded trans-copy slice.
//   Blocks BB..2BB-1 : log-norm for batch b=bi-BB via MFMA + folded gold-path
//                      score and final LL (no workspace round-trip).
// Pairing b <-> b+BB puts one V + one S block per CU; the two blocks keep
// INDEPENDENT barrier domains (single 16-wave fusion regressed: 587 vs 490).
// R3 lesson: `float C[32]` at VGPR_Count=52 means the compiler SANK the
// transition-column loads into the step loop (32 global re-loads/step).
// This round: named float4 c0..c7 / v0..v7 + hand-unrolled body to force
// register residency (expect ~90-100 VGPR; budget 128 at (512,4)).
__global__ __launch_bounds__(512, 4) void fwd_kernel(
        const float* __restrict__ em, const int* __restrict__ gtags,
        const int* __restrict__ mask, const float* __restrict__ trans,
        float* __restrict__ out_ll, float* __restrict__ out_trans,
        float* __restrict__ outp) {
    const int bi = blockIdx.x;
    const bool isV = bi < BB;
    const int b = isV ? bi : bi - BB;
    const int tid = threadIdx.x;
    const int w = tid >> 6;
    const int l = tid & 63;
    const int j = (l & 15) + 16 * w;   // column (V: unique per (w,l&15); S: same)
    const int q = l >> 4;              // V: i-chunk of 32; S: quad
    const int i0 = 32 * q;

    __shared__ __align__(16) float stA[144], stB[144];  // V alpha ping-pong
    __shared__ __align__(16) __bf16 sbf[2][NN];         // S state (bf16) dbl-buf
    __shared__ unsigned char bp_lds[TT * NN];           // V: 64 KB backpointers
    __shared__ unsigned char tags_lds[TT];
    __shared__ unsigned char map_lds[8 * NN];
    __shared__ int entry_sh[8];
    __shared__ int msk[TT];
    __shared__ float piv[2];
    __shared__ float sfin[NN];
    __shared__ float wsum[8];
    __shared__ float llnorm_sh;
    __shared__ int misc[2];                             // [0]=lastTag [1]=kacc

    msk[tid] = mask[b * TT + tid];

    const float* emb = em + (size_t)b * TT * NN;

    if (isV) {
        // Transition column j, rows i0..i0+31, held in 8 NAMED float4s.
        float4 c0, c1, c2, c3, c4, c5, c6, c7;
        {
            const float* tc = trans + (size_t)i0 * NN + j;
            #define LDC(cc, u) cc.x = tc[(4*u+0)*NN]; cc.y = tc[(4*u+1)*NN]; \
                               cc.z = tc[(4*u+2)*NN]; cc.w = tc[(4*u+3)*NN];
            LDC(c0, 0) LDC(c1, 1) LDC(c2, 2) LDC(c3, 3)
            LDC(c4, 4) LDC(c5, 5) LDC(c6, 6) LDC(c7, 7)
            #undef LDC
        }
        float st = 0.f;
        {
            float a0 = emb[j];
            st = a0;
            if (l < 16) stA[padidx(j)] = a0;
        }
        float e_next = emb[NN + j];
        __syncthreads();

        const float4* apA = (const float4*)(stA + 36 * q);
        const float4* apB = (const float4*)(stB + 36 * q);

        auto VSTEP = [&](int t, const float4* ap, float* dst) {
            const float e_cur = e_next;
            if (t + 1 < TT) e_next = emb[(size_t)(t + 1) * NN + j];
            const int m = msk[t];
            // 8 named ds_read_b128 issued before any consumption.
            float4 v0 = ap[0], v1 = ap[1], v2 = ap[2], v3 = ap[3],
                   v4 = ap[4], v5 = ap[5], v6 = ap[6], v7 = ap[7];
            float m0 = -INFINITY, m1 = -INFINITY, m2 = -INFINITY, m3 = -INFINITY;
            int u0 = 0, u1 = 0, u2 = 0, u3 = 0;
            #define CH(vv, cc, u) { \
                float a = vv.x + cc.x; u0 = (a > m0) ? u : u0; m0 = fmaxf(m0, a); \
                float bq = vv.y + cc.y; u1 = (bq > m1) ? u : u1; m1 = fmaxf(m1, bq); \
                float c = vv.z + cc.z; u2 = (c > m2) ? u : u2; m2 = fmaxf(m2, c); \
                float d = vv.w + cc.w; u3 = (d > m3) ? u : u3; m3 = fmaxf(m3, d); }
            CH(v0, c0, 0) CH(v1, c1, 1) CH(v2, c2, 2) CH(v3, c3, 3)
            CH(v4, c4, 4) CH(v5, c5, 5) CH(v6, c6, 6) CH(v7, c7, 7)
            #undef CH
            float bv = m0; int bx = i0 + 4 * u0;
            { int id = i0 + 4*u1 + 1; if (m1 > bv || (m1 == bv && id < bx)) { bv = m1; bx = id; } }
            { int id = i0 + 4*u2 + 2; if (m2 > bv || (m2 == bv && id < bx)) { bv = m2; bx = id; } }
            { int id = i0 + 4*u3 + 3; if (m3 > bv || (m3 == bv && id < bx)) { bv = m3; bx = id; } }
            #pragma unroll
            for (int off = 16; off <= 32; off <<= 1) {
                float ov = __shfl_xor(bv, off);
                int oi = __shfl_xor(bx, off);
                if (ov > bv || (ov == bv && oi < bx)) { bv = ov; bx = oi; }
            }
            if (l < 16) {
                float an; int bp;
                if (m) { an = bv + e_cur; bp = bx; }   // plain add = reference-exact
                else   { an = st;         bp = j;  }   // identity bp when masked
                st = an;
                dst[padidx(j)] = an;
                bp_lds[t * NN + j] = (unsigned char)bp;
            }
            __syncthreads();
        };

        for (int t = 1; t < TT - 1; t += 2) {
            VSTEP(t, apA, stB);
            VSTEP(t + 1, apB, stA);
        }
        VSTEP(TT - 1, apA, stB);   // final alpha in stB

        if (w == 0) {   // last-tag argmax (exact, first-index ties)
            float a0 = stB[padidx(2 * l)], a1 = stB[padidx(2 * l + 1)];
            int tg = wave_argmax128(a0, a1, l);
            if (l == 0) { misc[0] = tg; tags_lds[TT - 1] = (unsigned char)tg; }
        }
        if (tid < 64) out_trans[b * 64 + tid] = trans[b * 64 + tid];  // folded copy
        __syncthreads();
        // Phase 1: each wave maps all 128 entry tags through its 64-step chunk.
        const int lo = 64 * w + 1;
        const int hi = (w == 7) ? (TT - 1) : (64 * w + 64);
        {
            int tA = 2 * l, tB = 2 * l + 1;
            for (int t = hi; t >= lo; --t) {
                tA = bp_lds[t * NN + tA];
                tB = bp_lds[t * NN + tB];
            }
            map_lds[w * NN + 2 * l]     = (unsigned char)tA;
            map_lds[w * NN + 2 * l + 1] = (unsigned char)tB;
        }
        __syncthreads();
        // Phase 2: compose chunk maps -> true entry tag per chunk.
        if (tid == 0) {
            int e = misc[0];
            entry_sh[7] = e;
            for (int c = 7; c >= 1; --c) { e = map_lds[c * NN + e]; entry_sh[c - 1] = e; }
        }
        __syncthreads();
        // Phase 3: re-trace each chunk from its true entry.
        if (l == 0) {
            int tg = entry_sh[w];
            for (int t = hi; t >= lo; --t) {
                tg = bp_lds[t * NN + tg];
                tags_lds[t - 1] = (unsigned char)tg;
            }
        }
        __syncthreads();
        outp[(size_t)b * TT + tid] = (float)tags_lds[tid];
    } else {
        bf16x8 Bf[4];
        #pragma unroll
        for (int kc = 0; kc < 4; ++kc) {
            #pragma unroll
            for (int jj = 0; jj < 8; ++jj) {
                int row = kc * 32 + q * 8 + jj;
                Bf[kc][jj] = to_bf16(__expf(trans[(size_t)row * NN + j]));
            }
        }
        float ss = __expf(emb[j]);
        int kacc = 0;
        if (l < 16) sbf[0][j] = to_bf16(ss);
        if (tid == 0) piv[0] = ss;
        float e_next = emb[NN + j];
        __syncthreads();

        for (int t = 1; t < TT; ++t) {
            const float e_cur = e_next;
            if (t + 1 < TT) e_next = emb[(size_t)(t + 1) * NN + j];
            const int m = msk[t];
            const int p = (t - 1) & 1, qb = t & 1;
            if (m) {
                const __bf16* sp = sbf[p];
                floatx4 acc = {0.f, 0.f, 0.f, 0.f};
                #pragma unroll
                for (int kc = 0; kc < 4; ++kc) {
                    bf16x8 a = *(const bf16x8*)(sp + kc * 32 + q * 8);
                    acc = __builtin_amdgcn_mfma_f32_16x16x32_bf16(a, Bf[kc], acc, 0, 0, 0);
                }
                float dot = acc[0];                    // rows identical -> regs equal
                const float pv = piv[p];
                const int k = (int)(__float_as_uint(pv) >> 23) - 127;
                const float scale = __uint_as_float((unsigned)(127 - k) << 23);  // 2^-k
                ss = dot * scale * __expf(e_cur);
                if (tid == 0) kacc += k;
            }
            if (l < 16) sbf[qb][j] = to_bf16(ss);
            if (tid == 0) piv[qb] = ss;
            __syncthreads();
        }

        if (l < 16) sfin[j] = ss;
        if (tid == 0) misc[1] = kacc;
        __syncthreads();
        if (w == 0) {
            float v = sfin[2 * l] + sfin[2 * l + 1];
            v = wave_sum64(v);
            if (l == 0) llnorm_sh = __logf(v) + (float)misc[1] * LN2F;
        }
        // Folded gold-path score: one t per thread (TT == blockDim).
        float acc = 0.f;
        {
            int tg = gtags[b * TT + tid];
            float mf = (float)msk[tid];
            acc = emb[(size_t)tid * NN + tg] * mf;
            if (tid >= 1) {
                int tp = gtags[b * TT + tid - 1];
                acc += trans[tp * NN + tg] * mf;
            }
        }
        acc = wave_sum64(acc);
        if (l == 0) wsum[w] = acc;
        __syncthreads();
        if (tid == 0) {
            float s = 0.f;
            #pragma unroll
            for (int i = 0; i < 8; ++i) s += wsum[i];
            out_ll[b] = s - llnorm_sh;
        }
    }
}

extern "C" void kernel_launch(void* const* d_in, const int* in_sizes, int n_in,
                              void* d_out, int out_size, void* d_ws, size_t ws_size,
                              hipStream_t stream) {
    const float* em = (const float*)d_in[0];
    const int* gtags = (const int*)d_in[1];
    const int* mask = (const int*)d_in[2];
    const float* trans = (const float*)d_in[3];

    float* out = (float*)d_out;
    float* out_ll = out;
    float* out_trans = out + BB;
    float* out_pred = out + BB + NN * NN;

    hipLaunchKernelGGL(fwd_kernel, dim3(2 * BB), dim3(512), 0, stream,
                       em, gtags, mask, trans, out_ll, out_trans, out_pred);
}